// Round 13
// baseline (127.568 us; speedup 1.0000x reference)
//
#include <hip/hip_runtime.h>
#include <math.h>

#define MAXT 100000.0f
#define M_OUT 1024
#define BATCH 64
#define PITCH 1040      // 1025 real + pads covering 8-row prefetch overrun (<=1039)
#define NSEG 16
#define SEGLEN 64

#define WALL() __builtin_amdgcn_sched_barrier(0)

// ---------------------------------------------------------------------------
// Kernel 1: stable rank via u32 keys (21 mantissa bits || 11 index bits),
// SPLIT-J: 512-thread blocks; thread t (t<256) ranks key i over j in
// [0,516), thread t+256 ranks the same key over [516,1032); partials
// combined via LDS. Halves each thread's serial LDS-read chain (R11 rank was
// ~13 us, latency-bound at 1.25 waves/SIMD). Keys unique -> rank is a perm.
// Writes TRUE x to sx, byte row offsets to soff; rewrites pads every launch
// (ws re-poisoned 0xAA).
// ---------------------------------------------------------------------------
__global__ __launch_bounds__(512) void rank_kernel(const float* __restrict__ X,
                                                   float* __restrict__ sx,
                                                   int* __restrict__ soff) {
    const int b   = blockIdx.y;
    const int tid = threadIdx.x;            // 0..511
    const int t   = tid & 255;              // key slot within block
    const int i   = blockIdx.x * 256 + t;   // key index 0..1279
    __shared__ __align__(16) unsigned keys[1032];
    __shared__ int part[256];

    // true x for the scatter (keys are lossy); bias i==1024 -> 1.0f
    const float myx = (i < 1024) ? X[b * 1024 + i] : 1.0f;

#pragma unroll
    for (int c = 0; c < 2; ++c) {
        const int ii = c * 512 + tid;
        const float v = X[b * 1024 + ii];
        keys[ii] = (((__float_as_uint(v) - 0x3F800000u) >> 2) << 11) | (unsigned)ii;
    }
    if (tid == 0) keys[1024] = 1024u;                       // bias: mantissa 0 | idx 1024
    else if (tid < 8) keys[1024 + tid] = 0xFFFFFFFFu;       // pads: > all real keys
    __syncthreads();

    const unsigned ki = keys[(i < 1032) ? i : 1031];        // guard OOB LDS read
    const int j0 = (tid < 256) ? 0 : 516;
    int r0 = 0, r1 = 0;
#pragma unroll 8
    for (int j = j0; j < j0 + 512; j += 8) {
        const uint4 a = *(const uint4*)&keys[j];
        const uint4 c = *(const uint4*)&keys[j + 4];
        r0 += (int)(a.x < ki) + (int)(a.y < ki) + (int)(a.z < ki) + (int)(a.w < ki);
        r1 += (int)(c.x < ki) + (int)(c.y < ki) + (int)(c.z < ki) + (int)(c.w < ki);
    }
    // 516 = 64*8 + 4: last quad of the half-range
    {
        const uint4 a = *(const uint4*)&keys[j0 + 512];
        r0 += (int)(a.x < ki) + (int)(a.y < ki) + (int)(a.z < ki) + (int)(a.w < ki);
    }
    if (tid >= 256) part[t] = r0 + r1;
    __syncthreads();

    if (tid < 256) {
        if (i <= 1024) {
            const int rank = r0 + r1 + part[t];
            sx[b * PITCH + rank]   = myx;
            soff[b * PITCH + rank] = i * 4096;              // byte offset into W
        } else if (i < PITCH) {
            sx[b * PITCH + i] = MAXT; soff[b * PITCH + i] = 0;  // sentinels
        }
    }
}

// ---------------------------------------------------------------------------
// Kernel 2: decoupled two-pass K-scan (R9 shape: 4 cols/lane, 16 waves = 16
// segments), 8-row iterations with depth-1 prefetch at 8-row granularity:
// 8-16 float4 loads in flight per wave (R11 had 4; pass 1's 64-cyc compute
// per 4-row iter couldn't cover ~250-cyc L2 latency even x4 waves).
// Arithmetic chain order identical to R11 (absmax 16 expected unchanged).
// Step algebra: windows ordered in k -> min valid = FIRST valid (lock via bd
// sign); gates cross-multiplied, no div in loop; one IEEE div at the end.
// R12 bug: multi-statement macros used as unbraced loop bodies -> now
// do{...}while(0)-wrapped and loop bodies braced.
// ---------------------------------------------------------------------------
__global__ __launch_bounds__(1024, 4) void snn_scan(const float* __restrict__ W,
                                                    const float* __restrict__ sx,
                                                    const int* __restrict__ soff,
                                                    float* __restrict__ out) {
    const int b    = blockIdx.y;
    const int tid  = threadIdx.x;
    const int w    = tid >> 6;        // wave = K-segment id, 0..15
    const int lane = tid & 63;

    __shared__ __align__(16) float xs_s[PITCH];
    __shared__ __align__(16) int   off_s[PITCH];
    __shared__ __align__(16) float segw [NSEG][256];
    __shared__ __align__(16) float segwt[NSEG][256];
    __shared__ __align__(16) float best [NSEG][256];

    xs_s[tid]  = sx[b * PITCH + tid];
    off_s[tid] = soff[b * PITCH + tid];
    if (tid < PITCH - 1024) {
        xs_s[1024 + tid]  = sx[b * PITCH + 1024 + tid];
        off_s[1024 + tid] = soff[b * PITCH + 1024 + tid];
    }
    __syncthreads();

    const char* Wq = (const char*)W + (size_t)(blockIdx.x * 256 + lane * 4) * 4;
    const int4* off4 = (const int4*)off_s;
    const int k0 = w * SEGLEN;
    const int base = k0 >> 2;         // first int4 slot of this segment

#define LOAD8(dst, oA, oB)                                                     \
    do {                                                                       \
        dst[0] = *(const float4*)(Wq + (oA).x);                                \
        dst[1] = *(const float4*)(Wq + (oA).y);                                \
        dst[2] = *(const float4*)(Wq + (oA).z);                                \
        dst[3] = *(const float4*)(Wq + (oA).w);                                \
        dst[4] = *(const float4*)(Wq + (oB).x);                                \
        dst[5] = *(const float4*)(Wq + (oB).y);                                \
        dst[6] = *(const float4*)(Wq + (oB).z);                                \
        dst[7] = *(const float4*)(Wq + (oB).w);                                \
    } while (0)

    float cw0 = 0, cw1 = 0, cw2 = 0, cw3 = 0;
    float ct0 = 0, ct1 = 0, ct2 = 0, ct3 = 0;

#define ACC(wv, xx)                                                            \
    do {                                                                       \
        cw0 = __fadd_rn(cw0, (wv).x); ct0 = __builtin_fmaf((wv).x, (xx), ct0); \
        cw1 = __fadd_rn(cw1, (wv).y); ct1 = __builtin_fmaf((wv).y, (xx), ct1); \
        cw2 = __fadd_rn(cw2, (wv).z); ct2 = __builtin_fmaf((wv).z, (xx), ct2); \
        cw3 = __fadd_rn(cw3, (wv).w); ct3 = __builtin_fmaf((wv).w, (xx), ct3); \
    } while (0)

    // ---- pass 1: segment sums, 8-row pipelined ----
    {
        int4 oA = off4[base], oB = off4[base + 1];
        float4 a[8];
        LOAD8(a, oA, oB);
        int4 oC = off4[base + 2], oD = off4[base + 3];
        for (int it = 0; it < 8; ++it) {
            WALL();
            float4 n[8];
            LOAD8(n, oC, oD);                               // rows for iter it+1
            const int idx = base + 2 * it + 4;              // offsets for iter it+2
            const int4 oE = off4[idx], oF = off4[idx + 1];  // (pads safe, <=1039)
            WALL();
            const int k = k0 + it * 8;
#pragma unroll
            for (int r = 0; r < 8; ++r) { ACC(a[r], xs_s[k + r]); }
#pragma unroll
            for (int r = 0; r < 8; ++r) { a[r] = n[r]; }
            oC = oE; oD = oF;
        }
    }
    *(float4*)&segw[w][lane * 4]  = make_float4(cw0, cw1, cw2, cw3);
    *(float4*)&segwt[w][lane * 4] = make_float4(ct0, ct1, ct2, ct3);
    __syncthreads();

    // ---- exclusive prefix over segments (ascending s) ----
    cw0 = cw1 = cw2 = cw3 = ct0 = ct1 = ct2 = ct3 = 0.0f;
    for (int s = 0; s < w; ++s) {
        const float4 a = *(const float4*)&segw[s][lane * 4];
        const float4 t = *(const float4*)&segwt[s][lane * 4];
        cw0 = __fadd_rn(cw0, a.x); cw1 = __fadd_rn(cw1, a.y);
        cw2 = __fadd_rn(cw2, a.z); cw3 = __fadd_rn(cw3, a.w);
        ct0 = __fadd_rn(ct0, t.x); ct1 = __fadd_rn(ct1, t.y);
        ct2 = __fadd_rn(ct2, t.z); ct3 = __fadd_rn(ct3, t.w);
    }

    // ---- pass 2: gated scan with first-valid lock, 8-row pipelined ----
    float bn0 = 0, bn1 = 0, bn2 = 0, bn3 = 0;
    float bd0 = -1.0f, bd1 = -1.0f, bd2 = -1.0f, bd3 = -1.0f;

#define GATE(cwv, ctv, bnv, bdv, wvv, xx, xxn)                                 \
    do {                                                                       \
        cwv = __fadd_rn(cwv, (wvv));                                           \
        ctv = __builtin_fmaf((wvv), (xx), ctv);                                \
        const float dn = __fadd_rn(cwv, -1.0f);                                \
        const bool v = (ctv >= __fmul_rn((xx), dn))                            \
                     & (ctv <= __fmul_rn((xxn), dn));                          \
        const bool u = v & (bdv < 0.0f);                                       \
        bnv = u ? ctv : bnv;                                                   \
        bdv = u ? dn  : bdv;                                                   \
    } while (0)

#define GATE4(wv, xx, xxn)                                                     \
    do {                                                                       \
        GATE(cw0, ct0, bn0, bd0, (wv).x, (xx), (xxn));                         \
        GATE(cw1, ct1, bn1, bd1, (wv).y, (xx), (xxn));                         \
        GATE(cw2, ct2, bn2, bd2, (wv).z, (xx), (xxn));                         \
        GATE(cw3, ct3, bn3, bd3, (wv).w, (xx), (xxn));                         \
    } while (0)

    {
        int4 oA = off4[base], oB = off4[base + 1];
        float4 a[8];
        LOAD8(a, oA, oB);
        int4 oC = off4[base + 2], oD = off4[base + 3];
        for (int it = 0; it < 8; ++it) {
            WALL();
            float4 n[8];
            LOAD8(n, oC, oD);
            const int idx = base + 2 * it + 4;
            const int4 oE = off4[idx], oF = off4[idx + 1];
            WALL();
            const int k = k0 + it * 8;
#pragma unroll
            for (int r = 0; r < 8; ++r) { GATE4(a[r], xs_s[k + r], xs_s[k + r + 1]); }
#pragma unroll
            for (int r = 0; r < 8; ++r) { a[r] = n[r]; }
            oC = oE; oD = oF;
        }
        if (w == NSEG - 1) {
            // epilogue row 1024: a[0] was loaded from off4[base+16].x == off_s[1024]
            GATE4(a[0], xs_s[1024], xs_s[1025]);            // xs_s[1025] = MAXT pad
        }
    }

    const float c0 = (bd0 > 0.0f) ? bn0 / bd0 : MAXT;       // exact IEEE div
    const float c1 = (bd1 > 0.0f) ? bn1 / bd1 : MAXT;
    const float c2 = (bd2 > 0.0f) ? bn2 / bd2 : MAXT;
    const float c3 = (bd3 > 0.0f) ? bn3 / bd3 : MAXT;
    *(float4*)&best[w][lane * 4] = make_float4(c0, c1, c2, c3);
    __syncthreads();

    // ---- cross-segment min + store ----
    if (tid < 256) {
        float r = best[0][tid];
#pragma unroll
        for (int s = 1; s < NSEG; ++s) r = fminf(r, best[s][tid]);
        out[b * M_OUT + blockIdx.x * 256 + tid] = r;
    }
}

extern "C" void kernel_launch(void* const* d_in, const int* in_sizes, int n_in,
                              void* d_out, int out_size, void* d_ws, size_t ws_size,
                              hipStream_t stream) {
    const float* X = (const float*)d_in[0];   // [64, 1024]
    const float* W = (const float*)d_in[1];   // [1025, 1024]
    float* out = (float*)d_out;               // [64, 1024]

    float* sx   = (float*)d_ws;                                        // [64, PITCH]
    int*   soff = (int*)((char*)d_ws + BATCH * PITCH * sizeof(float)); // [64, PITCH]

    dim3 g1(5, BATCH);
    rank_kernel<<<g1, 512, 0, stream>>>(X, sx, soff);

    dim3 g2(M_OUT / 256, BATCH);
    snn_scan<<<g2, 1024, 0, stream>>>(W, sx, soff, out);
}

// Round 14
// 97.485 us; speedup vs baseline: 1.3086x; 1.3086x over previous
//
#include <hip/hip_runtime.h>
#include <math.h>

#define MAXT 100000.0f
#define M_OUT 1024
#define BATCH 64
#define PITCH 1036      // 1025 real + pads covering depth-2 offset prefetch (<=1031)
#define NSEG 16
#define SEGLEN 64

#define WALL() __builtin_amdgcn_sched_barrier(0)

// ---------------------------------------------------------------------------
// Kernel 1 (R13, verified): stable rank via u32 keys, SPLIT-J halves the
// serial LDS chain: 512-thread blocks; thread t (<256) ranks key i over
// j in [0,516), thread t+256 over [516,1032); partials combined via LDS.
// key = (mantissa bits >> 2) << 11 | index — ties fall to index order =
// adjacent-swap perturbation, compensated (validated R9-R13: absmax 16).
// Writes TRUE x to sx, byte row offsets to soff; rewrites pads every launch.
// ---------------------------------------------------------------------------
__global__ __launch_bounds__(512) void rank_kernel(const float* __restrict__ X,
                                                   float* __restrict__ sx,
                                                   int* __restrict__ soff) {
    const int b   = blockIdx.y;
    const int tid = threadIdx.x;            // 0..511
    const int t   = tid & 255;              // key slot within block
    const int i   = blockIdx.x * 256 + t;   // key index 0..1279
    __shared__ __align__(16) unsigned keys[1032];
    __shared__ int part[256];

    const float myx = (i < 1024) ? X[b * 1024 + i] : 1.0f;

#pragma unroll
    for (int c = 0; c < 2; ++c) {
        const int ii = c * 512 + tid;
        const float v = X[b * 1024 + ii];
        keys[ii] = (((__float_as_uint(v) - 0x3F800000u) >> 2) << 11) | (unsigned)ii;
    }
    if (tid == 0) keys[1024] = 1024u;                       // bias: mantissa 0 | idx 1024
    else if (tid < 8) keys[1024 + tid] = 0xFFFFFFFFu;       // pads: > all real keys
    __syncthreads();

    const unsigned ki = keys[(i < 1032) ? i : 1031];        // guard OOB LDS read
    const int j0 = (tid < 256) ? 0 : 516;
    int r0 = 0, r1 = 0;
#pragma unroll 8
    for (int j = j0; j < j0 + 512; j += 8) {
        const uint4 a = *(const uint4*)&keys[j];
        const uint4 c = *(const uint4*)&keys[j + 4];
        r0 += (int)(a.x < ki) + (int)(a.y < ki) + (int)(a.z < ki) + (int)(a.w < ki);
        r1 += (int)(c.x < ki) + (int)(c.y < ki) + (int)(c.z < ki) + (int)(c.w < ki);
    }
    {   // 516 = 512 + last quad of the half-range
        const uint4 a = *(const uint4*)&keys[j0 + 512];
        r0 += (int)(a.x < ki) + (int)(a.y < ki) + (int)(a.z < ki) + (int)(a.w < ki);
    }
    if (tid >= 256) part[t] = r0 + r1;
    __syncthreads();

    if (tid < 256) {
        if (i <= 1024) {
            const int rank = r0 + r1 + part[t];
            sx[b * PITCH + rank]   = myx;
            soff[b * PITCH + rank] = i * 4096;              // byte offset into W
        } else if (i < PITCH) {
            sx[b * PITCH + i] = MAXT; soff[b * PITCH + i] = 0;  // sentinels
        }
    }
}

// ---------------------------------------------------------------------------
// Kernel 2 (R11, verified — R13's 8-row variant spilled: WRITE_SIZE 80 MB):
// decoupled two-pass K-scan, 4 cols/lane, 16 waves = 16 segments, explicit
// ping-pong prefetch: W for iter i+1 + offsets for iter i+2 loaded before
// computing iter i, pinned by sched_barrier walls. Register footprint kept
// <= 64 VGPRs (two 4xfloat4 buffers) — the allocator won't go past 64 here.
// Step algebra: windows ordered in k -> min valid = FIRST valid (lock via bd
// sign); gates cross-multiplied, no div in loop; one IEEE div at the end.
// ---------------------------------------------------------------------------
__global__ __launch_bounds__(1024, 4) void snn_scan(const float* __restrict__ W,
                                                    const float* __restrict__ sx,
                                                    const int* __restrict__ soff,
                                                    float* __restrict__ out) {
    const int b    = blockIdx.y;
    const int tid  = threadIdx.x;
    const int w    = tid >> 6;        // wave = K-segment id, 0..15
    const int lane = tid & 63;

    __shared__ __align__(16) float xs_s[PITCH];
    __shared__ __align__(16) int   off_s[PITCH];
    __shared__ __align__(16) float segw [NSEG][256];
    __shared__ __align__(16) float segwt[NSEG][256];
    __shared__ __align__(16) float best [NSEG][256];

    xs_s[tid]  = sx[b * PITCH + tid];
    off_s[tid] = soff[b * PITCH + tid];
    if (tid < PITCH - 1024) {
        xs_s[1024 + tid]  = sx[b * PITCH + 1024 + tid];
        off_s[1024 + tid] = soff[b * PITCH + 1024 + tid];
    }
    __syncthreads();

    const char* Wq = (const char*)W + (size_t)(blockIdx.x * 256 + lane * 4) * 4;
    const int4* off4 = (const int4*)off_s;
    const int k0 = w * SEGLEN;
    const int base = k0 >> 2;

    float cw0 = 0, cw1 = 0, cw2 = 0, cw3 = 0;
    float ct0 = 0, ct1 = 0, ct2 = 0, ct3 = 0;

#define LOAD4(o, a0, a1, a2, a3)                                               \
    a0 = *(const float4*)(Wq + (o).x); a1 = *(const float4*)(Wq + (o).y);      \
    a2 = *(const float4*)(Wq + (o).z); a3 = *(const float4*)(Wq + (o).w);

#define ACC(wv, xx)                                                            \
    cw0 = __fadd_rn(cw0, (wv).x); ct0 = __builtin_fmaf((wv).x, (xx), ct0);     \
    cw1 = __fadd_rn(cw1, (wv).y); ct1 = __builtin_fmaf((wv).y, (xx), ct1);     \
    cw2 = __fadd_rn(cw2, (wv).z); ct2 = __builtin_fmaf((wv).z, (xx), ct2);     \
    cw3 = __fadd_rn(cw3, (wv).w); ct3 = __builtin_fmaf((wv).w, (xx), ct3);

    // ---- pass 1: segment sums, prefetch-pipelined ----
    {
        int4 oc = off4[base];
        int4 on = off4[base + 1];
        float4 a0, a1, a2, a3;
        LOAD4(oc, a0, a1, a2, a3);
        for (int it = 0; it < 16; ++it) {
            WALL();
            float4 n0, n1, n2, n3;
            LOAD4(on, n0, n1, n2, n3);              // W for iter it+1
            const int4 of = off4[base + it + 2];    // offsets for iter it+2 (pads safe)
            WALL();
            const int k = k0 + it * 4;
            ACC(a0, xs_s[k]);     ACC(a1, xs_s[k + 1]);
            ACC(a2, xs_s[k + 2]); ACC(a3, xs_s[k + 3]);
            a0 = n0; a1 = n1; a2 = n2; a3 = n3; on = of;
        }
    }
    *(float4*)&segw[w][lane * 4]  = make_float4(cw0, cw1, cw2, cw3);
    *(float4*)&segwt[w][lane * 4] = make_float4(ct0, ct1, ct2, ct3);
    __syncthreads();

    // ---- exclusive prefix over segments (ascending s) ----
    cw0 = cw1 = cw2 = cw3 = ct0 = ct1 = ct2 = ct3 = 0.0f;
    for (int s = 0; s < w; ++s) {
        const float4 a = *(const float4*)&segw[s][lane * 4];
        const float4 t = *(const float4*)&segwt[s][lane * 4];
        cw0 = __fadd_rn(cw0, a.x); cw1 = __fadd_rn(cw1, a.y);
        cw2 = __fadd_rn(cw2, a.z); cw3 = __fadd_rn(cw3, a.w);
        ct0 = __fadd_rn(ct0, t.x); ct1 = __fadd_rn(ct1, t.y);
        ct2 = __fadd_rn(ct2, t.z); ct3 = __fadd_rn(ct3, t.w);
    }

    // ---- pass 2: gated scan with first-valid lock, prefetch-pipelined ----
    float bn0 = 0, bn1 = 0, bn2 = 0, bn3 = 0;
    float bd0 = -1.0f, bd1 = -1.0f, bd2 = -1.0f, bd3 = -1.0f;

#define GATE(cwv, ctv, bnv, bdv, wvv, xx, xxn)                                 \
    {                                                                          \
        cwv = __fadd_rn(cwv, (wvv));                                           \
        ctv = __builtin_fmaf((wvv), (xx), ctv);                                \
        const float dn = __fadd_rn(cwv, -1.0f);                                \
        const bool v = (ctv >= __fmul_rn((xx), dn))                            \
                     & (ctv <= __fmul_rn((xxn), dn));                          \
        const bool u = v & (bdv < 0.0f);                                       \
        bnv = u ? ctv : bnv;                                                   \
        bdv = u ? dn  : bdv;                                                   \
    }

#define GATE4(wv, xx, xxn)                                                     \
    GATE(cw0, ct0, bn0, bd0, (wv).x, (xx), (xxn))                              \
    GATE(cw1, ct1, bn1, bd1, (wv).y, (xx), (xxn))                              \
    GATE(cw2, ct2, bn2, bd2, (wv).z, (xx), (xxn))                              \
    GATE(cw3, ct3, bn3, bd3, (wv).w, (xx), (xxn))

    {
        int4 oc = off4[base];
        int4 on = off4[base + 1];
        float4 a0, a1, a2, a3;
        LOAD4(oc, a0, a1, a2, a3);
        for (int it = 0; it < 16; ++it) {
            WALL();
            float4 n0, n1, n2, n3;
            LOAD4(on, n0, n1, n2, n3);
            const int4 of = off4[base + it + 2];
            WALL();
            const int k = k0 + it * 4;
            const float xa = xs_s[k],     xb = xs_s[k + 1];
            const float xc = xs_s[k + 2], xd = xs_s[k + 3], xe = xs_s[k + 4];
            GATE4(a0, xa, xb); GATE4(a1, xb, xc);
            GATE4(a2, xc, xd); GATE4(a3, xd, xe);
            a0 = n0; a1 = n1; a2 = n2; a3 = n3; on = of;
        }
        if (w == NSEG - 1) {
            // epilogue row 1024: a0 now holds W[off_s[1024]] (loaded at it=15)
            const float xe = xs_s[1024], xen = xs_s[1025];   // xen = MAXT pad
            GATE4(a0, xe, xen);
        }
    }

    const float c0 = (bd0 > 0.0f) ? bn0 / bd0 : MAXT;   // exact IEEE div
    const float c1 = (bd1 > 0.0f) ? bn1 / bd1 : MAXT;
    const float c2 = (bd2 > 0.0f) ? bn2 / bd2 : MAXT;
    const float c3 = (bd3 > 0.0f) ? bn3 / bd3 : MAXT;
    *(float4*)&best[w][lane * 4] = make_float4(c0, c1, c2, c3);
    __syncthreads();

    // ---- cross-segment min + store ----
    if (tid < 256) {
        float r = best[0][tid];
#pragma unroll
        for (int s = 1; s < NSEG; ++s) r = fminf(r, best[s][tid]);
        out[b * M_OUT + blockIdx.x * 256 + tid] = r;
    }
}

extern "C" void kernel_launch(void* const* d_in, const int* in_sizes, int n_in,
                              void* d_out, int out_size, void* d_ws, size_t ws_size,
                              hipStream_t stream) {
    const float* X = (const float*)d_in[0];   // [64, 1024]
    const float* W = (const float*)d_in[1];   // [1025, 1024]
    float* out = (float*)d_out;               // [64, 1024]

    float* sx   = (float*)d_ws;                                        // [64, PITCH]
    int*   soff = (int*)((char*)d_ws + BATCH * PITCH * sizeof(float)); // [64, PITCH]

    dim3 g1(5, BATCH);
    rank_kernel<<<g1, 512, 0, stream>>>(X, sx, soff);

    dim3 g2(M_OUT / 256, BATCH);
    snn_scan<<<g2, 1024, 0, stream>>>(W, sx, soff, out);
}